// Round 3
// baseline (212.404 us; speedup 1.0000x reference)
//
#include <hip/hip_runtime.h>
#include <hip/hip_bf16.h>

typedef __bf16 v8bf __attribute__((ext_vector_type(8)));
typedef float f32x4 __attribute__((ext_vector_type(4)));

__device__ __forceinline__ float bf2f(ushort u) {
    union { uint i; float f; } c; c.i = ((uint)u) << 16; return c.f;
}
__device__ __forceinline__ ushort f2bf(float f) {
    union { float f; uint i; } c; c.f = f;
    uint r = c.i + 0x7fffu + ((c.i >> 16) & 1u);
    return (ushort)(r >> 16);
}

// ---------------------------------------------------------------------------
// fp32 -> bf16 conversion (weights), 8 elems/thread
// ---------------------------------------------------------------------------
__global__ __launch_bounds__(256)
void cvt_bf16_kernel(const float* __restrict__ src, ushort* __restrict__ dst, long n)
{
    long i = ((long)blockIdx.x * blockDim.x + threadIdx.x) * 8;
    if (i >= n) return;
    float4 a0 = *(const float4*)&src[i];
    float4 a1 = *(const float4*)&src[i + 4];
    ushort4 o0, o1;
    o0.x = f2bf(a0.x); o0.y = f2bf(a0.y); o0.z = f2bf(a0.z); o0.w = f2bf(a0.w);
    o1.x = f2bf(a1.x); o1.y = f2bf(a1.y); o1.z = f2bf(a1.z); o1.w = f2bf(a1.w);
    *(ushort4*)&dst[i]     = o0;
    *(ushort4*)&dst[i + 4] = o1;
}

// ---------------------------------------------------------------------------
// meas = cos(x + theta_attn[i & 63])   (fp32 in, bf16 out)
// ---------------------------------------------------------------------------
__global__ __launch_bounds__(256)
void meas_kernel(const float* __restrict__ x, const float* __restrict__ theta,
                 ushort* __restrict__ meas, long n)
{
    long i = ((long)blockIdx.x * blockDim.x + threadIdx.x) * 8;
    if (i >= n) return;
    float4 a0 = *(const float4*)&x[i];
    float4 a1 = *(const float4*)&x[i + 4];
    int tb = (int)(i & 63);
    float4 t0 = *(const float4*)&theta[tb];
    float4 t1 = *(const float4*)&theta[tb + 4];
    ushort4 o0, o1;
    o0.x = f2bf(cosf(a0.x + t0.x));
    o0.y = f2bf(cosf(a0.y + t0.y));
    o0.z = f2bf(cosf(a0.z + t0.z));
    o0.w = f2bf(cosf(a0.w + t0.w));
    o1.x = f2bf(cosf(a1.x + t1.x));
    o1.y = f2bf(cosf(a1.y + t1.y));
    o1.z = f2bf(cosf(a1.z + t1.z));
    o1.w = f2bf(cosf(a1.w + t1.w));
    *(ushort4*)&meas[i]     = o0;
    *(ushort4*)&meas[i + 4] = o1;
}

// ---------------------------------------------------------------------------
// C = A @ B^T  (A: MxK bf16 row-major, B: NxK bf16 row-major, C: MxN bf16)
// 128x128 tile, BK=32, 4 waves of 64x64, mfma_f32_16x16x32_bf16
// ---------------------------------------------------------------------------
#define BM 128
#define BN 128
#define BKK 32
#define LDT 40   // padded LDS row length (elems): 80B stride -> 2-way alias only

template<int RELU>
__global__ __launch_bounds__(256)
void gemm_bt(const ushort* __restrict__ A, const ushort* __restrict__ B,
             ushort* __restrict__ C, int M, int N, int K)
{
    __shared__ ushort sA[BM * LDT];
    __shared__ ushort sB[BN * LDT];
    const int t    = threadIdx.x;
    const int lane = t & 63;
    const int wid  = t >> 6;
    const int wr   = (wid >> 1) * 64;
    const int wc   = (wid & 1) * 64;
    const long brow = (long)blockIdx.y * BM;
    const long bcol = (long)blockIdx.x * BN;

    const int r0 = t >> 2;          // staging row (and +64)
    const int c0 = (t & 3) * 8;     // staging col offset (elems)

    f32x4 acc[4][4];
    const f32x4 z = {0.f, 0.f, 0.f, 0.f};
    for (int m = 0; m < 4; m++)
        for (int n = 0; n < 4; n++) acc[m][n] = z;

    const int fr = lane & 15;
    const int fk = (lane >> 4) * 8;

    for (int k0 = 0; k0 < K; k0 += BKK) {
        __syncthreads();
        {
            const ushort* ga = A + (brow + r0) * (long)K + k0 + c0;
            *(uint4*)&sA[r0 * LDT + c0]          = *(const uint4*)ga;
            *(uint4*)&sA[(r0 + 64) * LDT + c0]   = *(const uint4*)(ga + 64L * K);
            const ushort* gb = B + (bcol + r0) * (long)K + k0 + c0;
            *(uint4*)&sB[r0 * LDT + c0]          = *(const uint4*)gb;
            *(uint4*)&sB[(r0 + 64) * LDT + c0]   = *(const uint4*)(gb + 64L * K);
        }
        __syncthreads();
        v8bf a[4], b[4];
        for (int m = 0; m < 4; m++)
            a[m] = *(const v8bf*)&sA[(wr + m * 16 + fr) * LDT + fk];
        for (int n = 0; n < 4; n++)
            b[n] = *(const v8bf*)&sB[(wc + n * 16 + fr) * LDT + fk];
        for (int m = 0; m < 4; m++)
            for (int n = 0; n < 4; n++)
                acc[m][n] = __builtin_amdgcn_mfma_f32_16x16x32_bf16(a[m], b[n], acc[m][n], 0, 0, 0);
    }

    const int cr  = (lane >> 4) * 4;
    const int cc2 = lane & 15;
    for (int m = 0; m < 4; m++)
        for (int n = 0; n < 4; n++) {
            long row = brow + wr + m * 16 + cr;
            long col = bcol + wc + n * 16 + cc2;
            for (int j = 0; j < 4; j++) {
                float v = acc[m][n][j];
                if (RELU) v = v > 0.f ? v : 0.f;
                C[(row + j) * (long)N + col] = f2bf(v);
            }
        }
}

// ---------------------------------------------------------------------------
// LN1: x1 = LayerNorm(x + attn)*g1 + b1 ; q = cos(x1[:, :64] + theta_ffn)
// x, g1, b1, theta_ffn fp32; attn, x1, q bf16
// ---------------------------------------------------------------------------
__global__ __launch_bounds__(256)
void ln1_kernel(const float* __restrict__ x, const ushort* __restrict__ attn,
                const float* __restrict__ g1, const float* __restrict__ b1,
                const float* __restrict__ theta_ffn,
                ushort* __restrict__ x1, ushort* __restrict__ q)
{
    const int row = blockIdx.x;
    const int t   = threadIdx.x;
    const long base = (long)row * 1024 + t * 4;
    float4  xu = *(const float4*)&x[base];
    ushort4 au = *(const ushort4*)&attn[base];
    float y0 = xu.x + bf2f(au.x);
    float y1 = xu.y + bf2f(au.y);
    float y2 = xu.z + bf2f(au.z);
    float y3 = xu.w + bf2f(au.w);
    float s  = y0 + y1 + y2 + y3;
    float ss = y0 * y0 + y1 * y1 + y2 * y2 + y3 * y3;
    for (int off = 32; off > 0; off >>= 1) {
        s  += __shfl_down(s, off, 64);
        ss += __shfl_down(ss, off, 64);
    }
    __shared__ float red[8];
    const int lane = t & 63, wid = t >> 6;
    if (lane == 0) { red[wid] = s; red[4 + wid] = ss; }
    __syncthreads();
    s  = red[0] + red[1] + red[2] + red[3];
    ss = red[4] + red[5] + red[6] + red[7];
    const float mu   = s * (1.0f / 1024.0f);
    const float var  = ss * (1.0f / 1024.0f) - mu * mu;
    const float rstd = rsqrtf(var + 1e-5f);
    float4 gu = *(const float4*)&g1[t * 4];
    float4 bu = *(const float4*)&b1[t * 4];
    float o0 = (y0 - mu) * rstd * gu.x + bu.x;
    float o1 = (y1 - mu) * rstd * gu.y + bu.y;
    float o2 = (y2 - mu) * rstd * gu.z + bu.z;
    float o3 = (y3 - mu) * rstd * gu.w + bu.w;
    ushort4 ou; ou.x = f2bf(o0); ou.y = f2bf(o1); ou.z = f2bf(o2); ou.w = f2bf(o3);
    *(ushort4*)&x1[base] = ou;
    if (t < 16) {
        float4 tu = *(const float4*)&theta_ffn[t * 4];
        ushort4 qu;
        qu.x = f2bf(cosf(o0 + tu.x));
        qu.y = f2bf(cosf(o1 + tu.y));
        qu.z = f2bf(cosf(o2 + tu.z));
        qu.w = f2bf(cosf(o3 + tu.w));
        *(ushort4*)&q[(long)row * 64 + t * 4] = qu;
    }
}

// ---------------------------------------------------------------------------
// LN2: out = LayerNorm(x1 + ffn)*g2 + b2   (out = d_out, FP32 — the
// reference's output dtype; round-2 failure was writing bf16 here)
// ---------------------------------------------------------------------------
__global__ __launch_bounds__(256)
void ln2_kernel(const ushort* __restrict__ x1, const ushort* __restrict__ ffn,
                const float* __restrict__ g2, const float* __restrict__ b2,
                float* __restrict__ out)
{
    const int row = blockIdx.x;
    const int t   = threadIdx.x;
    const long base = (long)row * 1024 + t * 4;
    ushort4 xu = *(const ushort4*)&x1[base];
    ushort4 au = *(const ushort4*)&ffn[base];
    float y0 = bf2f(xu.x) + bf2f(au.x);
    float y1 = bf2f(xu.y) + bf2f(au.y);
    float y2 = bf2f(xu.z) + bf2f(au.z);
    float y3 = bf2f(xu.w) + bf2f(au.w);
    float s  = y0 + y1 + y2 + y3;
    float ss = y0 * y0 + y1 * y1 + y2 * y2 + y3 * y3;
    for (int off = 32; off > 0; off >>= 1) {
        s  += __shfl_down(s, off, 64);
        ss += __shfl_down(ss, off, 64);
    }
    __shared__ float red[8];
    const int lane = t & 63, wid = t >> 6;
    if (lane == 0) { red[wid] = s; red[4 + wid] = ss; }
    __syncthreads();
    s  = red[0] + red[1] + red[2] + red[3];
    ss = red[4] + red[5] + red[6] + red[7];
    const float mu   = s * (1.0f / 1024.0f);
    const float var  = ss * (1.0f / 1024.0f) - mu * mu;
    const float rstd = rsqrtf(var + 1e-5f);
    float4 gu = *(const float4*)&g2[t * 4];
    float4 bu = *(const float4*)&b2[t * 4];
    float4 ou;
    ou.x = (y0 - mu) * rstd * gu.x + bu.x;
    ou.y = (y1 - mu) * rstd * gu.y + bu.y;
    ou.z = (y2 - mu) * rstd * gu.z + bu.z;
    ou.w = (y3 - mu) * rstd * gu.w + bu.w;
    *(float4*)&out[base] = ou;
}

// ---------------------------------------------------------------------------
extern "C" void kernel_launch(void* const* d_in, const int* in_sizes, int n_in,
                              void* d_out, int out_size, void* d_ws, size_t ws_size,
                              hipStream_t stream)
{
    const int E = 1024, FFN = 4096;
    const long T = 8192;                   // B*S tokens
    const long NE = T * E;                 // 8388608

    const float* x       = (const float*)d_in[0];
    const float* th_attn = (const float*)d_in[1];
    const float* Wc      = (const float*)d_in[2];
    const float* g1      = (const float*)d_in[3];
    const float* b1      = (const float*)d_in[4];
    const float* th_ffn  = (const float*)d_in[5];
    const float* W1      = (const float*)d_in[6];
    const float* W2      = (const float*)d_in[7];
    const float* g2      = (const float*)d_in[8];
    const float* b2      = (const float*)d_in[9];
    float* out = (float*)d_out;

    // workspace carve (all bf16)
    ushort* ws   = (ushort*)d_ws;
    ushort* meas = ws;  ws += NE;              // 16.8 MB (reused for W2 bf16 later)
    ushort* attn = ws;  ws += NE;
    ushort* x1b  = ws;  ws += NE;
    ushort* q    = ws;  ws += T * 64;
    ushort* h    = ws;  ws += T * FFN;
    ushort* ffn  = ws;  ws += NE;
    ushort* wcb  = ws;  ws += (long)E * E;     // Wc bf16
    ushort* w1b  = ws;  ws += (long)FFN * 64;  // W1 bf16
    ushort* w2b  = meas;                       // W2 bf16 overlays meas (dead after GEMM1)
    if (ws_size < (size_t)((char*)ws - (char*)d_ws)) return;

    const long nWc = (long)E * E, nW1 = (long)FFN * 64, nW2 = (long)E * FFN;

    cvt_bf16_kernel<<<dim3((int)(nWc / 2048)), 256, 0, stream>>>(Wc, wcb, nWc);
    cvt_bf16_kernel<<<dim3((int)(nW1 / 2048)), 256, 0, stream>>>(W1, w1b, nW1);
    meas_kernel<<<dim3((int)(NE / 2048)), 256, 0, stream>>>(x, th_attn, meas, NE);
    gemm_bt<0><<<dim3(E / BN, (int)(T / BM)), 256, 0, stream>>>(meas, wcb, attn, (int)T, E, E);
    cvt_bf16_kernel<<<dim3((int)(nW2 / 2048)), 256, 0, stream>>>(W2, w2b, nW2);
    ln1_kernel<<<dim3((int)T), 256, 0, stream>>>(x, attn, g1, b1, th_ffn, x1b, q);
    gemm_bt<1><<<dim3(FFN / BN, (int)(T / BM)), 256, 0, stream>>>(q, w1b, h, (int)T, FFN, 64);
    gemm_bt<0><<<dim3(E / BN, (int)(T / BM)), 256, 0, stream>>>(h, w2b, ffn, (int)T, E, FFN);
    ln2_kernel<<<dim3((int)T), 256, 0, stream>>>(x1b, ffn, g2, b2, out);
}

// Round 4
// 193.244 us; speedup vs baseline: 1.0991x; 1.0991x over previous
//
#include <hip/hip_runtime.h>
#include <hip/hip_bf16.h>

typedef __bf16 v8bf __attribute__((ext_vector_type(8)));
typedef float f32x4 __attribute__((ext_vector_type(4)));

__device__ __forceinline__ float bf2f(ushort u) {
    union { uint i; float f; } c; c.i = ((uint)u) << 16; return c.f;
}
__device__ __forceinline__ ushort f2bf(float f) {
    union { float f; uint i; } c; c.f = f;
    uint r = c.i + 0x7fffu + ((c.i >> 16) & 1u);
    return (ushort)(r >> 16);
}

// global -> LDS direct DMA, 16B per lane. LDS dest must be wave-uniform base;
// HW writes base + lane*16. Global src is per-lane.
__device__ __forceinline__ void gld16(const ushort* g, ushort* l) {
    __builtin_amdgcn_global_load_lds(
        (const __attribute__((address_space(1))) uint*)(uintptr_t)g,
        (__attribute__((address_space(3))) uint*)(uint)(uintptr_t)l,
        16, 0, 0);
}

// ---------------------------------------------------------------------------
// fp32 -> bf16 conversion (weights), 8 elems/thread
// ---------------------------------------------------------------------------
__global__ __launch_bounds__(256)
void cvt_bf16_kernel(const float* __restrict__ src, ushort* __restrict__ dst, long n)
{
    long i = ((long)blockIdx.x * blockDim.x + threadIdx.x) * 8;
    if (i >= n) return;
    float4 a0 = *(const float4*)&src[i];
    float4 a1 = *(const float4*)&src[i + 4];
    ushort4 o0, o1;
    o0.x = f2bf(a0.x); o0.y = f2bf(a0.y); o0.z = f2bf(a0.z); o0.w = f2bf(a0.w);
    o1.x = f2bf(a1.x); o1.y = f2bf(a1.y); o1.z = f2bf(a1.z); o1.w = f2bf(a1.w);
    *(ushort4*)&dst[i]     = o0;
    *(ushort4*)&dst[i + 4] = o1;
}

// ---------------------------------------------------------------------------
// meas = cos(x + theta_attn[i & 63])   (fp32 in, bf16 out)
// ---------------------------------------------------------------------------
__global__ __launch_bounds__(256)
void meas_kernel(const float* __restrict__ x, const float* __restrict__ theta,
                 ushort* __restrict__ meas, long n)
{
    long i = ((long)blockIdx.x * blockDim.x + threadIdx.x) * 8;
    if (i >= n) return;
    float4 a0 = *(const float4*)&x[i];
    float4 a1 = *(const float4*)&x[i + 4];
    int tb = (int)(i & 63);
    float4 t0 = *(const float4*)&theta[tb];
    float4 t1 = *(const float4*)&theta[tb + 4];
    ushort4 o0, o1;
    o0.x = f2bf(cosf(a0.x + t0.x));
    o0.y = f2bf(cosf(a0.y + t0.y));
    o0.z = f2bf(cosf(a0.z + t0.z));
    o0.w = f2bf(cosf(a0.w + t0.w));
    o1.x = f2bf(cosf(a1.x + t1.x));
    o1.y = f2bf(cosf(a1.y + t1.y));
    o1.z = f2bf(cosf(a1.z + t1.z));
    o1.w = f2bf(cosf(a1.w + t1.w));
    *(ushort4*)&meas[i]     = o0;
    *(ushort4*)&meas[i + 4] = o1;
}

// ---------------------------------------------------------------------------
// C = A @ B^T  (A: MxK bf16 row-major, B: NxK bf16 row-major, C: MxN bf16)
// 128x128 tile, BK=32, 4 waves of 64x64, mfma_f32_16x16x32_bf16.
// m97 structure: global_load_lds width=16 staging into LINEAR (unpadded) LDS.
// T1 XCD-chunked block swizzle (requires nwg % 8 == 0 — all our grids comply).
// ---------------------------------------------------------------------------
#define BM 128
#define BN 128
#define BKK 32

template<int RELU>
__global__ __launch_bounds__(256)
void gemm_bt(const ushort* __restrict__ A, const ushort* __restrict__ B,
             ushort* __restrict__ C, int M, int N, int K)
{
    __shared__ ushort sA[BM * BKK];   // 8 KB, linear: row r at byte r*64
    __shared__ ushort sB[BN * BKK];   // 8 KB
    const int t    = threadIdx.x;
    const int lane = t & 63;
    const int wid  = t >> 6;

    // XCD-chunked swizzle: hardware round-robins original wg id across 8 XCDs;
    // remap so each XCD owns a contiguous chunk of the logical tile order.
    int wg = blockIdx.y * gridDim.x + blockIdx.x;
    const int chunk = (gridDim.x * gridDim.y) >> 3;
    wg = (wg & 7) * chunk + (wg >> 3);
    const int bx = wg % gridDim.x;
    const int by = wg / gridDim.x;

    const int wr   = (wid >> 1) * 64;
    const int wc   = (wid & 1) * 64;
    const long brow = (long)by * BM;
    const long bcol = (long)bx * BN;

    // staging: wave `wid` fills rows [wid*32, wid*32+32) of sA and sB,
    // two 16-row gld16 issues per matrix. lane l -> row ls, elems lc..lc+7.
    const int ls = lane >> 2;
    const int lc = (lane & 3) * 8;
    const int srow = wid * 32;
    const ushort* pa = A + (brow + srow + ls) * (long)K + lc;
    const ushort* pb = B + (bcol + srow + ls) * (long)K + lc;
    ushort* la0 = &sA[srow * BKK];
    ushort* la1 = &sA[(srow + 16) * BKK];
    ushort* lb0 = &sB[srow * BKK];
    ushort* lb1 = &sB[(srow + 16) * BKK];

    f32x4 acc[4][4];
    const f32x4 z = {0.f, 0.f, 0.f, 0.f};
    for (int m = 0; m < 4; m++)
        for (int n = 0; n < 4; n++) acc[m][n] = z;

    const int fr = lane & 15;
    const int fk = (lane >> 4) * 8;

    for (int k0 = 0; k0 < K; k0 += BKK) {
        __syncthreads();
        gld16(pa + k0,           la0);
        gld16(pa + 16L * K + k0, la1);
        gld16(pb + k0,           lb0);
        gld16(pb + 16L * K + k0, lb1);
        __syncthreads();   // compiler emits s_waitcnt vmcnt(0) before barrier
        v8bf a[4], b[4];
        for (int m = 0; m < 4; m++)
            a[m] = *(const v8bf*)&sA[(wr + m * 16 + fr) * BKK + fk];
        for (int n = 0; n < 4; n++)
            b[n] = *(const v8bf*)&sB[(wc + n * 16 + fr) * BKK + fk];
        for (int m = 0; m < 4; m++)
            for (int n = 0; n < 4; n++)
                acc[m][n] = __builtin_amdgcn_mfma_f32_16x16x32_bf16(a[m], b[n], acc[m][n], 0, 0, 0);
    }

    const int cr  = (lane >> 4) * 4;
    const int cc2 = lane & 15;
    for (int m = 0; m < 4; m++)
        for (int n = 0; n < 4; n++) {
            long row = brow + wr + m * 16 + cr;
            long col = bcol + wc + n * 16 + cc2;
            for (int j = 0; j < 4; j++) {
                float v = acc[m][n][j];
                if (RELU) v = v > 0.f ? v : 0.f;
                C[(row + j) * (long)N + col] = f2bf(v);
            }
        }
}

// ---------------------------------------------------------------------------
// LN1: x1 = LayerNorm(x + attn)*g1 + b1 ; q = cos(x1[:, :64] + theta_ffn)
// ---------------------------------------------------------------------------
__global__ __launch_bounds__(256)
void ln1_kernel(const float* __restrict__ x, const ushort* __restrict__ attn,
                const float* __restrict__ g1, const float* __restrict__ b1,
                const float* __restrict__ theta_ffn,
                ushort* __restrict__ x1, ushort* __restrict__ q)
{
    const int row = blockIdx.x;
    const int t   = threadIdx.x;
    const long base = (long)row * 1024 + t * 4;
    float4  xu = *(const float4*)&x[base];
    ushort4 au = *(const ushort4*)&attn[base];
    float y0 = xu.x + bf2f(au.x);
    float y1 = xu.y + bf2f(au.y);
    float y2 = xu.z + bf2f(au.z);
    float y3 = xu.w + bf2f(au.w);
    float s  = y0 + y1 + y2 + y3;
    float ss = y0 * y0 + y1 * y1 + y2 * y2 + y3 * y3;
    for (int off = 32; off > 0; off >>= 1) {
        s  += __shfl_down(s, off, 64);
        ss += __shfl_down(ss, off, 64);
    }
    __shared__ float red[8];
    const int lane = t & 63, wid = t >> 6;
    if (lane == 0) { red[wid] = s; red[4 + wid] = ss; }
    __syncthreads();
    s  = red[0] + red[1] + red[2] + red[3];
    ss = red[4] + red[5] + red[6] + red[7];
    const float mu   = s * (1.0f / 1024.0f);
    const float var  = ss * (1.0f / 1024.0f) - mu * mu;
    const float rstd = rsqrtf(var + 1e-5f);
    float4 gu = *(const float4*)&g1[t * 4];
    float4 bu = *(const float4*)&b1[t * 4];
    float o0 = (y0 - mu) * rstd * gu.x + bu.x;
    float o1 = (y1 - mu) * rstd * gu.y + bu.y;
    float o2 = (y2 - mu) * rstd * gu.z + bu.z;
    float o3 = (y3 - mu) * rstd * gu.w + bu.w;
    ushort4 ou; ou.x = f2bf(o0); ou.y = f2bf(o1); ou.z = f2bf(o2); ou.w = f2bf(o3);
    *(ushort4*)&x1[base] = ou;
    if (t < 16) {
        float4 tu = *(const float4*)&theta_ffn[t * 4];
        ushort4 qu;
        qu.x = f2bf(cosf(o0 + tu.x));
        qu.y = f2bf(cosf(o1 + tu.y));
        qu.z = f2bf(cosf(o2 + tu.z));
        qu.w = f2bf(cosf(o3 + tu.w));
        *(ushort4*)&q[(long)row * 64 + t * 4] = qu;
    }
}

// ---------------------------------------------------------------------------
// LN2: out = LayerNorm(x1 + ffn)*g2 + b2   (d_out is FP32)
// ---------------------------------------------------------------------------
__global__ __launch_bounds__(256)
void ln2_kernel(const ushort* __restrict__ x1, const ushort* __restrict__ ffn,
                const float* __restrict__ g2, const float* __restrict__ b2,
                float* __restrict__ out)
{
    const int row = blockIdx.x;
    const int t   = threadIdx.x;
    const long base = (long)row * 1024 + t * 4;
    ushort4 xu = *(const ushort4*)&x1[base];
    ushort4 au = *(const ushort4*)&ffn[base];
    float y0 = bf2f(xu.x) + bf2f(au.x);
    float y1 = bf2f(xu.y) + bf2f(au.y);
    float y2 = bf2f(xu.z) + bf2f(au.z);
    float y3 = bf2f(xu.w) + bf2f(au.w);
    float s  = y0 + y1 + y2 + y3;
    float ss = y0 * y0 + y1 * y1 + y2 * y2 + y3 * y3;
    for (int off = 32; off > 0; off >>= 1) {
        s  += __shfl_down(s, off, 64);
        ss += __shfl_down(ss, off, 64);
    }
    __shared__ float red[8];
    const int lane = t & 63, wid = t >> 6;
    if (lane == 0) { red[wid] = s; red[4 + wid] = ss; }
    __syncthreads();
    s  = red[0] + red[1] + red[2] + red[3];
    ss = red[4] + red[5] + red[6] + red[7];
    const float mu   = s * (1.0f / 1024.0f);
    const float var  = ss * (1.0f / 1024.0f) - mu * mu;
    const float rstd = rsqrtf(var + 1e-5f);
    float4 gu = *(const float4*)&g2[t * 4];
    float4 bu = *(const float4*)&b2[t * 4];
    float4 ou;
    ou.x = (y0 - mu) * rstd * gu.x + bu.x;
    ou.y = (y1 - mu) * rstd * gu.y + bu.y;
    ou.z = (y2 - mu) * rstd * gu.z + bu.z;
    ou.w = (y3 - mu) * rstd * gu.w + bu.w;
    *(float4*)&out[base] = ou;
}

// ---------------------------------------------------------------------------
extern "C" void kernel_launch(void* const* d_in, const int* in_sizes, int n_in,
                              void* d_out, int out_size, void* d_ws, size_t ws_size,
                              hipStream_t stream)
{
    const int E = 1024, FFN = 4096;
    const long T = 8192;                   // B*S tokens
    const long NE = T * E;                 // 8388608

    const float* x       = (const float*)d_in[0];
    const float* th_attn = (const float*)d_in[1];
    const float* Wc      = (const float*)d_in[2];
    const float* g1      = (const float*)d_in[3];
    const float* b1      = (const float*)d_in[4];
    const float* th_ffn  = (const float*)d_in[5];
    const float* W1      = (const float*)d_in[6];
    const float* W2      = (const float*)d_in[7];
    const float* g2      = (const float*)d_in[8];
    const float* b2      = (const float*)d_in[9];
    float* out = (float*)d_out;

    // workspace carve (all bf16)
    ushort* ws   = (ushort*)d_ws;
    ushort* meas = ws;  ws += NE;              // 16.8 MB (reused for W2 bf16 later)
    ushort* attn = ws;  ws += NE;
    ushort* x1b  = ws;  ws += NE;
    ushort* q    = ws;  ws += T * 64;
    ushort* h    = ws;  ws += T * FFN;
    ushort* ffn  = ws;  ws += NE;
    ushort* wcb  = ws;  ws += (long)E * E;     // Wc bf16
    ushort* w1b  = ws;  ws += (long)FFN * 64;  // W1 bf16
    ushort* w2b  = meas;                       // W2 bf16 overlays meas (dead after GEMM1)
    if (ws_size < (size_t)((char*)ws - (char*)d_ws)) return;

    const long nWc = (long)E * E, nW1 = (long)FFN * 64, nW2 = (long)E * FFN;

    cvt_bf16_kernel<<<dim3((int)(nWc / 2048)), 256, 0, stream>>>(Wc, wcb, nWc);
    cvt_bf16_kernel<<<dim3((int)(nW1 / 2048)), 256, 0, stream>>>(W1, w1b, nW1);
    meas_kernel<<<dim3((int)(NE / 2048)), 256, 0, stream>>>(x, th_attn, meas, NE);
    gemm_bt<0><<<dim3(E / BN, (int)(T / BM)), 256, 0, stream>>>(meas, wcb, attn, (int)T, E, E);
    cvt_bf16_kernel<<<dim3((int)(nW2 / 2048)), 256, 0, stream>>>(W2, w2b, nW2);
    ln1_kernel<<<dim3((int)T), 256, 0, stream>>>(x, attn, g1, b1, th_ffn, x1b, q);
    gemm_bt<1><<<dim3(FFN / BN, (int)(T / BM)), 256, 0, stream>>>(q, w1b, h, (int)T, FFN, 64);
    gemm_bt<0><<<dim3(E / BN, (int)(T / BM)), 256, 0, stream>>>(h, w2b, ffn, (int)T, E, FFN);
    ln2_kernel<<<dim3((int)T), 256, 0, stream>>>(x1b, ffn, g2, b2, out);
}

// Round 5
// 168.016 us; speedup vs baseline: 1.2642x; 1.1502x over previous
//
#include <hip/hip_runtime.h>
#include <hip/hip_bf16.h>

typedef __bf16 v8bf __attribute__((ext_vector_type(8)));
typedef float f32x4 __attribute__((ext_vector_type(4)));

__device__ __forceinline__ float bf2f(ushort u) {
    union { uint i; float f; } c; c.i = ((uint)u) << 16; return c.f;
}
__device__ __forceinline__ ushort f2bf(float f) {
    union { float f; uint i; } c; c.f = f;
    uint r = c.i + 0x7fffu + ((c.i >> 16) & 1u);
    return (ushort)(r >> 16);
}

// global -> LDS direct DMA, 16B per lane. LDS dest wave-uniform base; HW
// writes base + lane*16. Global src per-lane.
__device__ __forceinline__ void gld16(const ushort* g, ushort* l) {
    __builtin_amdgcn_global_load_lds(
        (const __attribute__((address_space(1))) uint*)(uintptr_t)g,
        (__attribute__((address_space(3))) uint*)(uint)(uintptr_t)l,
        16, 0, 0);
}

// ---------------------------------------------------------------------------
// fp32 -> bf16 conversion (weights)
// ---------------------------------------------------------------------------
__global__ __launch_bounds__(256)
void cvt_bf16_kernel(const float* __restrict__ src, ushort* __restrict__ dst, long n)
{
    long i = ((long)blockIdx.x * blockDim.x + threadIdx.x) * 8;
    if (i >= n) return;
    float4 a0 = *(const float4*)&src[i];
    float4 a1 = *(const float4*)&src[i + 4];
    ushort4 o0, o1;
    o0.x = f2bf(a0.x); o0.y = f2bf(a0.y); o0.z = f2bf(a0.z); o0.w = f2bf(a0.w);
    o1.x = f2bf(a1.x); o1.y = f2bf(a1.y); o1.z = f2bf(a1.z); o1.w = f2bf(a1.w);
    *(ushort4*)&dst[i]     = o0;
    *(ushort4*)&dst[i + 4] = o1;
}

// ---------------------------------------------------------------------------
// meas = cos(x + theta_attn[i & 63])   (fp32 in, bf16 out)
// ---------------------------------------------------------------------------
__global__ __launch_bounds__(256)
void meas_kernel(const float* __restrict__ x, const float* __restrict__ theta,
                 ushort* __restrict__ meas, long n)
{
    long i = ((long)blockIdx.x * blockDim.x + threadIdx.x) * 8;
    if (i >= n) return;
    float4 a0 = *(const float4*)&x[i];
    float4 a1 = *(const float4*)&x[i + 4];
    int tb = (int)(i & 63);
    float4 t0 = *(const float4*)&theta[tb];
    float4 t1 = *(const float4*)&theta[tb + 4];
    ushort4 o0, o1;
    o0.x = f2bf(cosf(a0.x + t0.x));
    o0.y = f2bf(cosf(a0.y + t0.y));
    o0.z = f2bf(cosf(a0.z + t0.z));
    o0.w = f2bf(cosf(a0.w + t0.w));
    o1.x = f2bf(cosf(a1.x + t1.x));
    o1.y = f2bf(cosf(a1.y + t1.y));
    o1.z = f2bf(cosf(a1.z + t1.z));
    o1.w = f2bf(cosf(a1.w + t1.w));
    *(ushort4*)&meas[i]     = o0;
    *(ushort4*)&meas[i + 4] = o1;
}

// ---------------------------------------------------------------------------
// Pipelined GEMM: C = A @ B^T, BM=256 x BN=128, 512 thr / 8 waves (4M x 2N),
// K-slabs of 32 in a ring of 4 LDS slots (96 KB), counted vmcnt(9) pipeline,
// slot-XOR LDS swizzle (both-sides: inverse-swizzled global src + swizzled
// ds_read), setprio around the 16-MFMA cluster, T1 XCD-chunked swizzle.
// Requires K % 32 == 0, K/32 >= 4, M % 256 == 0, N % 128 == 0, nwg % 8 == 0.
// ---------------------------------------------------------------------------
__global__ __launch_bounds__(512)
void gemm_pipe(const ushort* __restrict__ A, const ushort* __restrict__ B,
               ushort* __restrict__ C, int M, int N, int K)
{
    // slab layout: A rows [256][32] at 0, B rows [128][32] at 8192 (elems)
    __shared__ ushort lds[4][12288];   // 4 x 24 KB = 96 KB

    const int t    = threadIdx.x;
    const int lane = t & 63;
    const int wid  = t >> 6;
    const int wm   = wid >> 1;     // 0..3 -> rows wm*64
    const int wn   = wid & 1;      // 0..1 -> cols wn*64

    int wg = blockIdx.y * gridDim.x + blockIdx.x;
    const int nwg = gridDim.x * gridDim.y;
    const int chunk = nwg >> 3;
    wg = (wg & 7) * chunk + (wg >> 3);
    const int bx = wg % gridDim.x;
    const int by = wg / gridDim.x;
    const long brow = (long)by * 256;
    const long bcol = (long)bx * 128;

    // staging addressing: lane -> local row rlo (16 rows/wave), slot j.
    // inverse swizzle on SOURCE: LDS slot j holds global k-slot j ^ (row&3).
    const int rlo  = lane >> 2;            // 0..15
    const int jsl  = lane & 3;
    const int gco  = ((jsl ^ (rlo & 3)) * 8);
    const ushort* pa0 = A + (brow + wid * 16 + rlo) * (long)K + gco;        // rows 0-127
    const ushort* pa1 = A + (brow + 128 + wid * 16 + rlo) * (long)K + gco;  // rows 128-255
    const ushort* pb  = B + (bcol + wid * 16 + rlo) * (long)K + gco;        // 128 rows

    f32x4 acc[4][4];
    const f32x4 z = {0.f, 0.f, 0.f, 0.f};
    for (int m = 0; m < 4; m++)
        for (int n = 0; n < 4; n++) acc[m][n] = z;

    const int fr = lane & 15;
    const int ks = (((lane >> 4) ^ (fr & 3)) * 8);   // swizzled k-slot (elems)

    auto stage = [&](int s) {
        const int slot = s & 3;
        const long k0 = (long)s * 32;
        gld16(pa0 + k0, &lds[slot][(wid * 16) * 32]);
        gld16(pa1 + k0, &lds[slot][(128 + wid * 16) * 32]);
        gld16(pb  + k0, &lds[slot][8192 + (wid * 16) * 32]);
    };

    auto compute = [&](int s) {
        const int slot = s & 3;
        v8bf a[4], b[4];
        for (int m = 0; m < 4; m++)
            a[m] = *(const v8bf*)&lds[slot][(wm * 64 + m * 16 + fr) * 32 + ks];
        for (int n = 0; n < 4; n++)
            b[n] = *(const v8bf*)&lds[slot][8192 + (wn * 64 + n * 16 + fr) * 32 + ks];
        __builtin_amdgcn_s_setprio(1);
        for (int m = 0; m < 4; m++)
            for (int n = 0; n < 4; n++)
                acc[m][n] = __builtin_amdgcn_mfma_f32_16x16x32_bf16(a[m], b[n], acc[m][n], 0, 0, 0);
        __builtin_amdgcn_s_setprio(0);
    };

    const int S = K >> 5;          // slabs of 32
    stage(0); stage(1); stage(2);  // 9 loads in flight per wave

    for (int s = 0; s < S - 3; ++s) {
        stage(s + 3);                                   // slot (s+3)&3 == (s-1)&3: readers done at end-barrier of s-1
        asm volatile("s_waitcnt vmcnt(9)" ::: "memory"); // own slab-s loads done; 3 slabs stay in flight
        __builtin_amdgcn_s_barrier();                    // all waves' slab-s loads done
        compute(s);
        __builtin_amdgcn_s_barrier();                    // all reads of slot s&3 done
    }
    asm volatile("s_waitcnt vmcnt(6)" ::: "memory");
    __builtin_amdgcn_s_barrier();
    compute(S - 3);
    __builtin_amdgcn_s_barrier();
    asm volatile("s_waitcnt vmcnt(3)" ::: "memory");
    __builtin_amdgcn_s_barrier();
    compute(S - 2);
    __builtin_amdgcn_s_barrier();
    asm volatile("s_waitcnt vmcnt(0)" ::: "memory");
    __builtin_amdgcn_s_barrier();
    compute(S - 1);

    // epilogue: C/D layout col=lane&15, row=(lane>>4)*4+jj (m89-verified)
    const int cr  = (lane >> 4) * 4;
    const int cc2 = lane & 15;
    for (int m = 0; m < 4; m++)
        for (int n = 0; n < 4; n++) {
            long row = brow + wm * 64 + m * 16 + cr;
            long col = bcol + wn * 64 + n * 16 + cc2;
            for (int jj = 0; jj < 4; jj++)
                C[(row + jj) * (long)N + col] = f2bf(acc[m][n][jj]);
        }
}

// ---------------------------------------------------------------------------
// Fallback GEMM (round-4 proven): used for GEMM2 (K=64, too shallow to pipe).
// ---------------------------------------------------------------------------
#define BM 128
#define BN 128
#define BKK 32

template<int RELU>
__global__ __launch_bounds__(256)
void gemm_bt(const ushort* __restrict__ A, const ushort* __restrict__ B,
             ushort* __restrict__ C, int M, int N, int K)
{
    __shared__ ushort sA[BM * BKK];
    __shared__ ushort sB[BN * BKK];
    const int t    = threadIdx.x;
    const int lane = t & 63;
    const int wid  = t >> 6;

    int wg = blockIdx.y * gridDim.x + blockIdx.x;
    const int chunk = (gridDim.x * gridDim.y) >> 3;
    wg = (wg & 7) * chunk + (wg >> 3);
    const int bx = wg % gridDim.x;
    const int by = wg / gridDim.x;

    const int wr   = (wid >> 1) * 64;
    const int wc   = (wid & 1) * 64;
    const long brow = (long)by * BM;
    const long bcol = (long)bx * BN;

    const int ls = lane >> 2;
    const int lc = (lane & 3) * 8;
    const int srow = wid * 32;
    const ushort* pa = A + (brow + srow + ls) * (long)K + lc;
    const ushort* pb = B + (bcol + srow + ls) * (long)K + lc;
    ushort* la0 = &sA[srow * BKK];
    ushort* la1 = &sA[(srow + 16) * BKK];
    ushort* lb0 = &sB[srow * BKK];
    ushort* lb1 = &sB[(srow + 16) * BKK];

    f32x4 acc[4][4];
    const f32x4 z = {0.f, 0.f, 0.f, 0.f};
    for (int m = 0; m < 4; m++)
        for (int n = 0; n < 4; n++) acc[m][n] = z;

    const int fr = lane & 15;
    const int fk = (lane >> 4) * 8;

    for (int k0 = 0; k0 < K; k0 += BKK) {
        __syncthreads();
        gld16(pa + k0,           la0);
        gld16(pa + 16L * K + k0, la1);
        gld16(pb + k0,           lb0);
        gld16(pb + 16L * K + k0, lb1);
        __syncthreads();
        v8bf a[4], b[4];
        for (int m = 0; m < 4; m++)
            a[m] = *(const v8bf*)&sA[(wr + m * 16 + fr) * BKK + fk];
        for (int n = 0; n < 4; n++)
            b[n] = *(const v8bf*)&sB[(wc + n * 16 + fr) * BKK + fk];
        for (int m = 0; m < 4; m++)
            for (int n = 0; n < 4; n++)
                acc[m][n] = __builtin_amdgcn_mfma_f32_16x16x32_bf16(a[m], b[n], acc[m][n], 0, 0, 0);
    }

    const int cr  = (lane >> 4) * 4;
    const int cc2 = lane & 15;
    for (int m = 0; m < 4; m++)
        for (int n = 0; n < 4; n++) {
            long row = brow + wr + m * 16 + cr;
            long col = bcol + wc + n * 16 + cc2;
            for (int j = 0; j < 4; j++) {
                float v = acc[m][n][j];
                if (RELU) v = v > 0.f ? v : 0.f;
                C[(row + j) * (long)N + col] = f2bf(v);
            }
        }
}

// ---------------------------------------------------------------------------
// LN1: x1 = LayerNorm(x + attn)*g1 + b1 ; q = cos(x1[:, :64] + theta_ffn)
// ---------------------------------------------------------------------------
__global__ __launch_bounds__(256)
void ln1_kernel(const float* __restrict__ x, const ushort* __restrict__ attn,
                const float* __restrict__ g1, const float* __restrict__ b1,
                const float* __restrict__ theta_ffn,
                ushort* __restrict__ x1, ushort* __restrict__ q)
{
    const int row = blockIdx.x;
    const int t   = threadIdx.x;
    const long base = (long)row * 1024 + t * 4;
    float4  xu = *(const float4*)&x[base];
    ushort4 au = *(const ushort4*)&attn[base];
    float y0 = xu.x + bf2f(au.x);
    float y1 = xu.y + bf2f(au.y);
    float y2 = xu.z + bf2f(au.z);
    float y3 = xu.w + bf2f(au.w);
    float s  = y0 + y1 + y2 + y3;
    float ss = y0 * y0 + y1 * y1 + y2 * y2 + y3 * y3;
    for (int off = 32; off > 0; off >>= 1) {
        s  += __shfl_down(s, off, 64);
        ss += __shfl_down(ss, off, 64);
    }
    __shared__ float red[8];
    const int lane = t & 63, wid = t >> 6;
    if (lane == 0) { red[wid] = s; red[4 + wid] = ss; }
    __syncthreads();
    s  = red[0] + red[1] + red[2] + red[3];
    ss = red[4] + red[5] + red[6] + red[7];
    const float mu   = s * (1.0f / 1024.0f);
    const float var  = ss * (1.0f / 1024.0f) - mu * mu;
    const float rstd = rsqrtf(var + 1e-5f);
    float4 gu = *(const float4*)&g1[t * 4];
    float4 bu = *(const float4*)&b1[t * 4];
    float o0 = (y0 - mu) * rstd * gu.x + bu.x;
    float o1 = (y1 - mu) * rstd * gu.y + bu.y;
    float o2 = (y2 - mu) * rstd * gu.z + bu.z;
    float o3 = (y3 - mu) * rstd * gu.w + bu.w;
    ushort4 ou; ou.x = f2bf(o0); ou.y = f2bf(o1); ou.z = f2bf(o2); ou.w = f2bf(o3);
    *(ushort4*)&x1[base] = ou;
    if (t < 16) {
        float4 tu = *(const float4*)&theta_ffn[t * 4];
        ushort4 qu;
        qu.x = f2bf(cosf(o0 + tu.x));
        qu.y = f2bf(cosf(o1 + tu.y));
        qu.z = f2bf(cosf(o2 + tu.z));
        qu.w = f2bf(cosf(o3 + tu.w));
        *(ushort4*)&q[(long)row * 64 + t * 4] = qu;
    }
}

// ---------------------------------------------------------------------------
// LN2: out = LayerNorm(x1 + ffn)*g2 + b2   (d_out is FP32)
// ---------------------------------------------------------------------------
__global__ __launch_bounds__(256)
void ln2_kernel(const ushort* __restrict__ x1, const ushort* __restrict__ ffn,
                const float* __restrict__ g2, const float* __restrict__ b2,
                float* __restrict__ out)
{
    const int row = blockIdx.x;
    const int t   = threadIdx.x;
    const long base = (long)row * 1024 + t * 4;
    ushort4 xu = *(const ushort4*)&x1[base];
    ushort4 au = *(const ushort4*)&ffn[base];
    float y0 = bf2f(xu.x) + bf2f(au.x);
    float y1 = bf2f(xu.y) + bf2f(au.y);
    float y2 = bf2f(xu.z) + bf2f(au.z);
    float y3 = bf2f(xu.w) + bf2f(au.w);
    float s  = y0 + y1 + y2 + y3;
    float ss = y0 * y0 + y1 * y1 + y2 * y2 + y3 * y3;
    for (int off = 32; off > 0; off >>= 1) {
        s  += __shfl_down(s, off, 64);
        ss += __shfl_down(ss, off, 64);
    }
    __shared__ float red[8];
    const int lane = t & 63, wid = t >> 6;
    if (lane == 0) { red[wid] = s; red[4 + wid] = ss; }
    __syncthreads();
    s  = red[0] + red[1] + red[2] + red[3];
    ss = red[4] + red[5] + red[6] + red[7];
    const float mu   = s * (1.0f / 1024.0f);
    const float var  = ss * (1.0f / 1024.0f) - mu * mu;
    const float rstd = rsqrtf(var + 1e-5f);
    float4 gu = *(const float4*)&g2[t * 4];
    float4 bu = *(const float4*)&b2[t * 4];
    float4 ou;
    ou.x = (y0 - mu) * rstd * gu.x + bu.x;
    ou.y = (y1 - mu) * rstd * gu.y + bu.y;
    ou.z = (y2 - mu) * rstd * gu.z + bu.z;
    ou.w = (y3 - mu) * rstd * gu.w + bu.w;
    *(float4*)&out[base] = ou;
}

// ---------------------------------------------------------------------------
extern "C" void kernel_launch(void* const* d_in, const int* in_sizes, int n_in,
                              void* d_out, int out_size, void* d_ws, size_t ws_size,
                              hipStream_t stream)
{
    const int E = 1024, FFN = 4096;
    const long T = 8192;
    const long NE = T * E;

    const float* x       = (const float*)d_in[0];
    const float* th_attn = (const float*)d_in[1];
    const float* Wc      = (const float*)d_in[2];
    const float* g1      = (const float*)d_in[3];
    const float* b1      = (const float*)d_in[4];
    const float* th_ffn  = (const float*)d_in[5];
    const float* W1      = (const float*)d_in[6];
    const float* W2      = (const float*)d_in[7];
    const float* g2      = (const float*)d_in[8];
    const float* b2      = (const float*)d_in[9];
    float* out = (float*)d_out;

    ushort* ws   = (ushort*)d_ws;
    ushort* meas = ws;  ws += NE;
    ushort* attn = ws;  ws += NE;
    ushort* x1b  = ws;  ws += NE;
    ushort* q    = ws;  ws += T * 64;
    ushort* h    = ws;  ws += T * FFN;
    ushort* ffn  = ws;  ws += NE;
    ushort* wcb  = ws;  ws += (long)E * E;
    ushort* w1b  = ws;  ws += (long)FFN * 64;
    ushort* w2b  = meas;   // overlays meas (dead after GEMM1)
    if (ws_size < (size_t)((char*)ws - (char*)d_ws)) return;

    const long nWc = (long)E * E, nW1 = (long)FFN * 64, nW2 = (long)E * FFN;

    cvt_bf16_kernel<<<dim3((int)(nWc / 2048)), 256, 0, stream>>>(Wc, wcb, nWc);
    cvt_bf16_kernel<<<dim3((int)(nW1 / 2048)), 256, 0, stream>>>(W1, w1b, nW1);
    meas_kernel<<<dim3((int)(NE / 2048)), 256, 0, stream>>>(x, th_attn, meas, NE);
    // GEMM1: (8192 x 1024) = meas(8192x1024) @ Wc^T — pipelined
    gemm_pipe<<<dim3(E / 128, (int)(T / 256)), 512, 0, stream>>>(meas, wcb, attn, (int)T, E, E);
    cvt_bf16_kernel<<<dim3((int)(nW2 / 2048)), 256, 0, stream>>>(W2, w2b, nW2);
    ln1_kernel<<<dim3((int)T), 256, 0, stream>>>(x, attn, g1, b1, th_ffn, x1b, q);
    // GEMM2: K=64 too shallow for the pipe — round-4 kernel
    gemm_bt<1><<<dim3(FFN / BN, (int)(T / BM)), 256, 0, stream>>>(q, w1b, h, (int)T, FFN, 64);
    // GEMM3: (8192 x 1024) = h(8192x4096) @ W2^T — pipelined
    gemm_pipe<<<dim3(E / 128, (int)(T / 256)), 512, 0, stream>>>(h, w2b, ffn, (int)T, E, FFN);
    ln2_kernel<<<dim3((int)T), 256, 0, stream>>>(x1b, ffn, g2, b2, out);
}

// Round 7
// 162.925 us; speedup vs baseline: 1.3037x; 1.0312x over previous
//
#include <hip/hip_runtime.h>
#include <hip/hip_bf16.h>

typedef __bf16 v8bf __attribute__((ext_vector_type(8)));
typedef float f32x4 __attribute__((ext_vector_type(4)));

__device__ __forceinline__ float bf2f(ushort u) {
    union { uint i; float f; } c; c.i = ((uint)u) << 16; return c.f;
}
__device__ __forceinline__ ushort f2bf(float f) {
    union { float f; uint i; } c; c.f = f;
    uint r = c.i + 0x7fffu + ((c.i >> 16) & 1u);
    return (ushort)(r >> 16);
}

// global -> LDS direct DMA, 16B per lane. LDS dest wave-uniform base; HW
// writes base + lane*16. Global src per-lane.
__device__ __forceinline__ void gld16(const ushort* g, ushort* l) {
    __builtin_amdgcn_global_load_lds(
        (const __attribute__((address_space(1))) uint*)(uintptr_t)g,
        (__attribute__((address_space(3))) uint*)(uint)(uintptr_t)l,
        16, 0, 0);
}

// ---------------------------------------------------------------------------
// fp32 -> bf16 conversion (weights)
// ---------------------------------------------------------------------------
__global__ __launch_bounds__(256)
void cvt_bf16_kernel(const float* __restrict__ src, ushort* __restrict__ dst, long n)
{
    long i = ((long)blockIdx.x * blockDim.x + threadIdx.x) * 8;
    if (i >= n) return;
    float4 a0 = *(const float4*)&src[i];
    float4 a1 = *(const float4*)&src[i + 4];
    ushort4 o0, o1;
    o0.x = f2bf(a0.x); o0.y = f2bf(a0.y); o0.z = f2bf(a0.z); o0.w = f2bf(a0.w);
    o1.x = f2bf(a1.x); o1.y = f2bf(a1.y); o1.z = f2bf(a1.z); o1.w = f2bf(a1.w);
    *(ushort4*)&dst[i]     = o0;
    *(ushort4*)&dst[i + 4] = o1;
}

// ---------------------------------------------------------------------------
// meas = cos(x + theta_attn[i & 63])   (fp32 in, bf16 out)
// ---------------------------------------------------------------------------
__global__ __launch_bounds__(256)
void meas_kernel(const float* __restrict__ x, const float* __restrict__ theta,
                 ushort* __restrict__ meas, long n)
{
    long i = ((long)blockIdx.x * blockDim.x + threadIdx.x) * 8;
    if (i >= n) return;
    float4 a0 = *(const float4*)&x[i];
    float4 a1 = *(const float4*)&x[i + 4];
    int tb = (int)(i & 63);
    float4 t0 = *(const float4*)&theta[tb];
    float4 t1 = *(const float4*)&theta[tb + 4];
    ushort4 o0, o1;
    o0.x = f2bf(cosf(a0.x + t0.x));
    o0.y = f2bf(cosf(a0.y + t0.y));
    o0.z = f2bf(cosf(a0.z + t0.z));
    o0.w = f2bf(cosf(a0.w + t0.w));
    o1.x = f2bf(cosf(a1.x + t1.x));
    o1.y = f2bf(cosf(a1.y + t1.y));
    o1.z = f2bf(cosf(a1.z + t1.z));
    o1.w = f2bf(cosf(a1.w + t1.w));
    *(ushort4*)&meas[i]     = o0;
    *(ushort4*)&meas[i + 4] = o1;
}

// ---------------------------------------------------------------------------
// Pipelined GEMM: C = A @ B^T, BM=256 x BN=128, 512 thr / 8 waves (4M x 2N),
// BK=64 slabs (128B LDS rows = bank wrap) in a ring of 3 (144 KB LDS),
// counted vmcnt(12) (2 slabs in flight), T2 XOR swizzle chunk^=(row&7)
// applied both-sides (inverse-swizzled global src, swizzled ds_read),
// T5 setprio around MFMA clusters, T1 XCD-chunked block swizzle.
// Requires K % 64 == 0, K/64 >= 3, M % 256 == 0, N % 128 == 0, nwg % 8 == 0.
// ---------------------------------------------------------------------------
__global__ __launch_bounds__(512)
void gemm_pipe(const ushort* __restrict__ A, const ushort* __restrict__ B,
               ushort* __restrict__ C, int M, int N, int K)
{
    // slab: A [256 rows][64 elems] at 0, B [128 rows][64] at 16384 (ushort idx)
    __shared__ ushort lds[3][24576];   // 3 x 48 KB = 144 KB

    const int t    = threadIdx.x;
    const int lane = t & 63;
    const int wid  = t >> 6;
    const int wm   = wid >> 1;     // 0..3 -> 64-row band
    const int wn   = wid & 1;      // 0..1 -> 64-col band

    int wg = blockIdx.y * gridDim.x + blockIdx.x;
    const int nwg = gridDim.x * gridDim.y;
    const int chunk = nwg >> 3;
    wg = (wg & 7) * chunk + (wg >> 3);
    const int bx = wg % gridDim.x;
    const int by = wg / gridDim.x;
    const long brow = (long)by * 256;
    const long bcol = (long)bx * 128;

    // staging: gld16 writes LDS linearly (lane -> row lane>>3, chunk lane&7).
    // Inverse swizzle on SOURCE so swizzled reads find chunk c at slot c^(r&7):
    const int lr = lane >> 3;                 // row within 8-row group
    const int co = ((lane & 7) ^ lr) * 8;     // global k-chunk (elems)
    const ushort* pa = A + (brow + wid * 32 + lr) * (long)K + co;
    const ushort* pb = B + (bcol + wid * 16 + lr) * (long)K + co;

    f32x4 acc[4][4];
    const f32x4 z = {0.f, 0.f, 0.f, 0.f};
    for (int m = 0; m < 4; m++)
        for (int n = 0; n < 4; n++) acc[m][n] = z;

    const int fr = lane & 15;
    const int hi = lane >> 4;

    auto stage = [&](int s) {
        const int slot = s % 3;
        const long k0 = (long)s * 64;
        ushort* base = &lds[slot][0];
        #pragma unroll
        for (int g = 0; g < 4; ++g)
            gld16(pa + g * 8L * K + k0, base + (wid * 32 + g * 8) * 64);
        #pragma unroll
        for (int g = 0; g < 2; ++g)
            gld16(pb + g * 8L * K + k0, base + 16384 + (wid * 16 + g * 8) * 64);
    };

    auto compute = [&](int s) {
        const int slot = s % 3;
        const ushort* sa = &lds[slot][0];
        const ushort* sb = &lds[slot][16384];
        #pragma unroll
        for (int ks = 0; ks < 2; ++ks) {
            const int sw = ((ks * 4 + hi) ^ (fr & 7)) * 8;   // swizzled chunk
            v8bf a[4], b[4];
            #pragma unroll
            for (int m = 0; m < 4; m++)
                a[m] = *(const v8bf*)&sa[(wm * 64 + m * 16 + fr) * 64 + sw];
            #pragma unroll
            for (int n = 0; n < 4; n++)
                b[n] = *(const v8bf*)&sb[(wn * 64 + n * 16 + fr) * 64 + sw];
            __builtin_amdgcn_s_setprio(1);
            #pragma unroll
            for (int m = 0; m < 4; m++)
                #pragma unroll
                for (int n = 0; n < 4; n++)
                    acc[m][n] = __builtin_amdgcn_mfma_f32_16x16x32_bf16(a[m], b[n], acc[m][n], 0, 0, 0);
            __builtin_amdgcn_s_setprio(0);
        }
    };

    const int S = K >> 6;          // BK=64 slabs
    stage(0); stage(1);            // 12 loads in flight per wave

    for (int s = 0; s < S - 2; ++s) {
        stage(s + 2);                                    // slot (s+2)%3 free (readers of s-1 done)
        asm volatile("s_waitcnt vmcnt(12)" ::: "memory"); // own slab-s loads landed; 2 slabs in flight
        __builtin_amdgcn_s_barrier();                     // all waves' slab-s loads landed
        compute(s);
        __builtin_amdgcn_s_barrier();                     // all reads of slot s%3 done
    }
    asm volatile("s_waitcnt vmcnt(6)" ::: "memory");
    __builtin_amdgcn_s_barrier();
    compute(S - 2);
    __builtin_amdgcn_s_barrier();
    asm volatile("s_waitcnt vmcnt(0)" ::: "memory");
    __builtin_amdgcn_s_barrier();
    compute(S - 1);

    // epilogue: C/D layout col=lane&15, row=(lane>>4)*4+jj (m89-verified)
    const int cr  = (lane >> 4) * 4;
    const int cc2 = lane & 15;
    for (int m = 0; m < 4; m++)
        for (int n = 0; n < 4; n++) {
            long row = brow + wm * 64 + m * 16 + cr;
            long col = bcol + wn * 64 + n * 16 + cc2;
            for (int jj = 0; jj < 4; jj++)
                C[(row + jj) * (long)N + col] = f2bf(acc[m][n][jj]);
        }
}

// ---------------------------------------------------------------------------
// Fallback GEMM (round-4 proven): used for GEMM2 (K=64, too shallow to pipe).
// ---------------------------------------------------------------------------
#define BM 128
#define BN 128
#define BKK 32

template<int RELU>
__global__ __launch_bounds__(256)
void gemm_bt(const ushort* __restrict__ A, const ushort* __restrict__ B,
             ushort* __restrict__ C, int M, int N, int K)
{
    __shared__ ushort sA[BM * BKK];
    __shared__ ushort sB[BN * BKK];
    const int t    = threadIdx.x;
    const int lane = t & 63;
    const int wid  = t >> 6;

    int wg = blockIdx.y * gridDim.x + blockIdx.x;
    const int chunk = (gridDim.x * gridDim.y) >> 3;
    wg = (wg & 7) * chunk + (wg >> 3);
    const int bx = wg % gridDim.x;
    const int by = wg / gridDim.x;

    const int wr   = (wid >> 1) * 64;
    const int wc   = (wid & 1) * 64;
    const long brow = (long)by * BM;
    const long bcol = (long)bx * BN;

    const int ls = lane >> 2;
    const int lc = (lane & 3) * 8;
    const int srow = wid * 32;
    const ushort* pa = A + (brow + srow + ls) * (long)K + lc;
    const ushort* pb = B + (bcol + srow + ls) * (long)K + lc;
    ushort* la0 = &sA[srow * BKK];
    ushort* la1 = &sA[(srow + 16) * BKK];
    ushort* lb0 = &sB[srow * BKK];
    ushort* lb1 = &sB[(srow + 16) * BKK];

    f32x4 acc[4][4];
    const f32x4 z = {0.f, 0.f, 0.f, 0.f};
    for (int m = 0; m < 4; m++)
        for (int n = 0; n < 4; n++) acc[m][n] = z;

    const int fr = lane & 15;
    const int fk = (lane >> 4) * 8;

    for (int k0 = 0; k0 < K; k0 += BKK) {
        __syncthreads();
        gld16(pa + k0,           la0);
        gld16(pa + 16L * K + k0, la1);
        gld16(pb + k0,           lb0);
        gld16(pb + 16L * K + k0, lb1);
        __syncthreads();
        v8bf a[4], b[4];
        for (int m = 0; m < 4; m++)
            a[m] = *(const v8bf*)&sA[(wr + m * 16 + fr) * BKK + fk];
        for (int n = 0; n < 4; n++)
            b[n] = *(const v8bf*)&sB[(wc + n * 16 + fr) * BKK + fk];
        for (int m = 0; m < 4; m++)
            for (int n = 0; n < 4; n++)
                acc[m][n] = __builtin_amdgcn_mfma_f32_16x16x32_bf16(a[m], b[n], acc[m][n], 0, 0, 0);
    }

    const int cr  = (lane >> 4) * 4;
    const int cc2 = lane & 15;
    for (int m = 0; m < 4; m++)
        for (int n = 0; n < 4; n++) {
            long row = brow + wr + m * 16 + cr;
            long col = bcol + wc + n * 16 + cc2;
            for (int j = 0; j < 4; j++) {
                float v = acc[m][n][j];
                if (RELU) v = v > 0.f ? v : 0.f;
                C[(row + j) * (long)N + col] = f2bf(v);
            }
        }
}

// ---------------------------------------------------------------------------
// LN1: x1 = LayerNorm(x + attn)*g1 + b1 ; q = cos(x1[:, :64] + theta_ffn)
// ---------------------------------------------------------------------------
__global__ __launch_bounds__(256)
void ln1_kernel(const float* __restrict__ x, const ushort* __restrict__ attn,
                const float* __restrict__ g1, const float* __restrict__ b1,
                const float* __restrict__ theta_ffn,
                ushort* __restrict__ x1, ushort* __restrict__ q)
{
    const int row = blockIdx.x;
    const int t   = threadIdx.x;
    const long base = (long)row * 1024 + t * 4;
    float4  xu = *(const float4*)&x[base];
    ushort4 au = *(const ushort4*)&attn[base];
    float y0 = xu.x + bf2f(au.x);
    float y1 = xu.y + bf2f(au.y);
    float y2 = xu.z + bf2f(au.z);
    float y3 = xu.w + bf2f(au.w);
    float s  = y0 + y1 + y2 + y3;
    float ss = y0 * y0 + y1 * y1 + y2 * y2 + y3 * y3;
    for (int off = 32; off > 0; off >>= 1) {
        s  += __shfl_down(s, off, 64);
        ss += __shfl_down(ss, off, 64);
    }
    __shared__ float red[8];
    const int lane = t & 63, wid = t >> 6;
    if (lane == 0) { red[wid] = s; red[4 + wid] = ss; }
    __syncthreads();
    s  = red[0] + red[1] + red[2] + red[3];
    ss = red[4] + red[5] + red[6] + red[7];
    const float mu   = s * (1.0f / 1024.0f);
    const float var  = ss * (1.0f / 1024.0f) - mu * mu;
    const float rstd = rsqrtf(var + 1e-5f);
    float4 gu = *(const float4*)&g1[t * 4];
    float4 bu = *(const float4*)&b1[t * 4];
    float o0 = (y0 - mu) * rstd * gu.x + bu.x;
    float o1 = (y1 - mu) * rstd * gu.y + bu.y;
    float o2 = (y2 - mu) * rstd * gu.z + bu.z;
    float o3 = (y3 - mu) * rstd * gu.w + bu.w;
    ushort4 ou; ou.x = f2bf(o0); ou.y = f2bf(o1); ou.z = f2bf(o2); ou.w = f2bf(o3);
    *(ushort4*)&x1[base] = ou;
    if (t < 16) {
        float4 tu = *(const float4*)&theta_ffn[t * 4];
        ushort4 qu;
        qu.x = f2bf(cosf(o0 + tu.x));
        qu.y = f2bf(cosf(o1 + tu.y));
        qu.z = f2bf(cosf(o2 + tu.z));
        qu.w = f2bf(cosf(o3 + tu.w));
        *(ushort4*)&q[(long)row * 64 + t * 4] = qu;
    }
}

// ---------------------------------------------------------------------------
// LN2: out = LayerNorm(x1 + ffn)*g2 + b2   (d_out is FP32)
// ---------------------------------------------------------------------------
__global__ __launch_bounds__(256)
void ln2_kernel(const ushort* __restrict__ x1, const ushort* __restrict__ ffn,
                const float* __restrict__ g2, const float* __restrict__ b2,
                float* __restrict__ out)
{
    const int row = blockIdx.x;
    const int t   = threadIdx.x;
    const long base = (long)row * 1024 + t * 4;
    ushort4 xu = *(const ushort4*)&x1[base];
    ushort4 au = *(const ushort4*)&ffn[base];
    float y0 = bf2f(xu.x) + bf2f(au.x);
    float y1 = bf2f(xu.y) + bf2f(au.y);
    float y2 = bf2f(xu.z) + bf2f(au.z);
    float y3 = bf2f(xu.w) + bf2f(au.w);
    float s  = y0 + y1 + y2 + y3;
    float ss = y0 * y0 + y1 * y1 + y2 * y2 + y3 * y3;
    for (int off = 32; off > 0; off >>= 1) {
        s  += __shfl_down(s, off, 64);
        ss += __shfl_down(ss, off, 64);
    }
    __shared__ float red[8];
    const int lane = t & 63, wid = t >> 6;
    if (lane == 0) { red[wid] = s; red[4 + wid] = ss; }
    __syncthreads();
    s  = red[0] + red[1] + red[2] + red[3];
    ss = red[4] + red[5] + red[6] + red[7];
    const float mu   = s * (1.0f / 1024.0f);
    const float var  = ss * (1.0f / 1024.0f) - mu * mu;
    const float rstd = rsqrtf(var + 1e-5f);
    float4 gu = *(const float4*)&g2[t * 4];
    float4 bu = *(const float4*)&b2[t * 4];
    float4 ou;
    ou.x = (y0 - mu) * rstd * gu.x + bu.x;
    ou.y = (y1 - mu) * rstd * gu.y + bu.y;
    ou.z = (y2 - mu) * rstd * gu.z + bu.z;
    ou.w = (y3 - mu) * rstd * gu.w + bu.w;
    *(float4*)&out[base] = ou;
}

// ---------------------------------------------------------------------------
extern "C" void kernel_launch(void* const* d_in, const int* in_sizes, int n_in,
                              void* d_out, int out_size, void* d_ws, size_t ws_size,
                              hipStream_t stream)
{
    const int E = 1024, FFN = 4096;
    const long T = 8192;
    const long NE = T * E;

    const float* x       = (const float*)d_in[0];
    const float* th_attn = (const float*)d_in[1];
    const float* Wc      = (const float*)d_in[2];
    const float* g1      = (const float*)d_in[3];
    const float* b1      = (const float*)d_in[4];
    const float* th_ffn  = (const float*)d_in[5];
    const float* W1      = (const float*)d_in[6];
    const float* W2      = (const float*)d_in[7];
    const float* g2      = (const float*)d_in[8];
    const float* b2      = (const float*)d_in[9];
    float* out = (float*)d_out;

    ushort* ws   = (ushort*)d_ws;
    ushort* meas = ws;  ws += NE;
    ushort* attn = ws;  ws += NE;
    ushort* x1b  = ws;  ws += NE;
    ushort* q    = ws;  ws += T * 64;
    ushort* h    = ws;  ws += T * FFN;
    ushort* ffn  = ws;  ws += NE;
    ushort* wcb  = ws;  ws += (long)E * E;
    ushort* w1b  = ws;  ws += (long)FFN * 64;
    ushort* w2b  = meas;   // overlays meas (dead after GEMM1)
    if (ws_size < (size_t)((char*)ws - (char*)d_ws)) return;

    const long nWc = (long)E * E, nW1 = (long)FFN * 64, nW2 = (long)E * FFN;

    cvt_bf16_kernel<<<dim3((int)(nWc / 2048)), 256, 0, stream>>>(Wc, wcb, nWc);
    cvt_bf16_kernel<<<dim3((int)(nW1 / 2048)), 256, 0, stream>>>(W1, w1b, nW1);
    meas_kernel<<<dim3((int)(NE / 2048)), 256, 0, stream>>>(x, th_attn, meas, NE);
    // GEMM1: meas(8192x1024) @ Wc^T — pipelined (S=16)
    gemm_pipe<<<dim3(E / 128, (int)(T / 256)), 512, 0, stream>>>(meas, wcb, attn, (int)T, E, E);
    cvt_bf16_kernel<<<dim3((int)(nW2 / 2048)), 256, 0, stream>>>(W2, w2b, nW2);
    ln1_kernel<<<dim3((int)T), 256, 0, stream>>>(x, attn, g1, b1, th_ffn, x1b, q);
    // GEMM2: K=64 too shallow for the pipe — round-4 kernel
    gemm_bt<1><<<dim3(FFN / BN, (int)(T / BM)), 256, 0, stream>>>(q, w1b, h, (int)T, FFN, 64);
    // GEMM3: h(8192x4096) @ W2^T — pipelined (S=64)
    gemm_pipe<<<dim3(E / 128, (int)(T / 256)), 512, 0, stream>>>(h, w2b, ffn, (int)T, E, FFN);
    ln2_kernel<<<dim3((int)T), 256, 0, stream>>>(x1b, ffn, g2, b2, out);
}

// Round 8
// 157.910 us; speedup vs baseline: 1.3451x; 1.0318x over previous
//
#include <hip/hip_runtime.h>
#include <hip/hip_bf16.h>

typedef __bf16 v8bf __attribute__((ext_vector_type(8)));
typedef float f32x4 __attribute__((ext_vector_type(4)));

__device__ __forceinline__ float bf2f(ushort u) {
    union { uint i; float f; } c; c.i = ((uint)u) << 16; return c.f;
}
__device__ __forceinline__ ushort f2bf(float f) {
    union { float f; uint i; } c; c.f = f;
    uint r = c.i + 0x7fffu + ((c.i >> 16) & 1u);
    return (ushort)(r >> 16);
}

// global -> LDS direct DMA, 16B per lane. LDS dest wave-uniform base; HW
// writes base + lane*16. Global src per-lane.
__device__ __forceinline__ void gld16(const ushort* g, ushort* l) {
    __builtin_amdgcn_global_load_lds(
        (const __attribute__((address_space(1))) uint*)(uintptr_t)g,
        (__attribute__((address_space(3))) uint*)(uint)(uintptr_t)l,
        16, 0, 0);
}

// ---------------------------------------------------------------------------
// fp32 -> bf16 conversion (weights)
// ---------------------------------------------------------------------------
__global__ __launch_bounds__(256)
void cvt_bf16_kernel(const float* __restrict__ src, ushort* __restrict__ dst, long n)
{
    long i = ((long)blockIdx.x * blockDim.x + threadIdx.x) * 8;
    if (i >= n) return;
    float4 a0 = *(const float4*)&src[i];
    float4 a1 = *(const float4*)&src[i + 4];
    ushort4 o0, o1;
    o0.x = f2bf(a0.x); o0.y = f2bf(a0.y); o0.z = f2bf(a0.z); o0.w = f2bf(a0.w);
    o1.x = f2bf(a1.x); o1.y = f2bf(a1.y); o1.z = f2bf(a1.z); o1.w = f2bf(a1.w);
    *(ushort4*)&dst[i]     = o0;
    *(ushort4*)&dst[i + 4] = o1;
}

// ---------------------------------------------------------------------------
// meas = cos(x + theta_attn[i & 63])   (fp32 in, bf16 out)
// ---------------------------------------------------------------------------
__global__ __launch_bounds__(256)
void meas_kernel(const float* __restrict__ x, const float* __restrict__ theta,
                 ushort* __restrict__ meas, long n)
{
    long i = ((long)blockIdx.x * blockDim.x + threadIdx.x) * 8;
    if (i >= n) return;
    float4 a0 = *(const float4*)&x[i];
    float4 a1 = *(const float4*)&x[i + 4];
    int tb = (int)(i & 63);
    float4 t0 = *(const float4*)&theta[tb];
    float4 t1 = *(const float4*)&theta[tb + 4];
    ushort4 o0, o1;
    o0.x = f2bf(cosf(a0.x + t0.x));
    o0.y = f2bf(cosf(a0.y + t0.y));
    o0.z = f2bf(cosf(a0.z + t0.z));
    o0.w = f2bf(cosf(a0.w + t0.w));
    o1.x = f2bf(cosf(a1.x + t1.x));
    o1.y = f2bf(cosf(a1.y + t1.y));
    o1.z = f2bf(cosf(a1.z + t1.z));
    o1.w = f2bf(cosf(a1.w + t1.w));
    *(ushort4*)&meas[i]     = o0;
    *(ushort4*)&meas[i + 4] = o1;
}

// ---------------------------------------------------------------------------
// Pipelined GEMM v2: C = A @ B^T, BM=BN=128, BK=64, 256 thr / 4 waves
// (2M x 2N, wave tile 64x64), ring of 2 LDS slots (64 KB total ->
// 2 blocks/CU for cross-block overlap), counted vmcnt(8) (1 slab in
// flight), both-sides XOR swizzle chunk^=(row&7) (0 conflicts, r7-verified),
// setprio around MFMA clusters, T1 XCD-chunked block swizzle.
// Requires K % 64 == 0, K/64 >= 2, M % 128 == 0, N % 128 == 0, nwg % 8 == 0.
// ---------------------------------------------------------------------------
__global__ __launch_bounds__(256)
void gemm_pipe(const ushort* __restrict__ A, const ushort* __restrict__ B,
               ushort* __restrict__ C, int M, int N, int K)
{
    // slot: A [128 rows][64 elems] at 0, B [128 rows][64] at 8192 (ushort idx)
    __shared__ ushort lds[2][16384];   // 2 x 32 KB = 64 KB

    const int t    = threadIdx.x;
    const int lane = t & 63;
    const int wid  = t >> 6;
    const int wm   = wid >> 1;     // 0..1 -> 64-row band
    const int wn   = wid & 1;      // 0..1 -> 64-col band

    int wg = blockIdx.y * gridDim.x + blockIdx.x;
    const int nwg = gridDim.x * gridDim.y;
    const int chunk = nwg >> 3;
    wg = (wg & 7) * chunk + (wg >> 3);
    const int bx = wg % gridDim.x;
    const int by = wg / gridDim.x;
    const long brow = (long)by * 128;
    const long bcol = (long)bx * 128;

    // staging: gld16 writes LDS linearly (lane -> row lane>>3, chunk lane&7).
    // Inverse swizzle on SOURCE so swizzled reads find chunk c at slot c^(r&7):
    const int lr = lane >> 3;                 // row within 8-row group (0..7)
    const int co = ((lane & 7) ^ lr) * 8;     // global k-chunk (elems)
    const ushort* pa = A + (brow + wid * 32 + lr) * (long)K + co;
    const ushort* pb = B + (bcol + wid * 32 + lr) * (long)K + co;

    f32x4 acc[4][4];
    const f32x4 z = {0.f, 0.f, 0.f, 0.f};
    for (int m = 0; m < 4; m++)
        for (int n = 0; n < 4; n++) acc[m][n] = z;

    const int fr = lane & 15;
    const int hi = lane >> 4;

    auto stage = [&](int s) {
        const int slot = s & 1;
        const long k0 = (long)s * 64;
        ushort* base = &lds[slot][0];
        #pragma unroll
        for (int g = 0; g < 4; ++g)
            gld16(pa + g * 8L * K + k0, base + (wid * 32 + g * 8) * 64);
        #pragma unroll
        for (int g = 0; g < 4; ++g)
            gld16(pb + g * 8L * K + k0, base + 8192 + (wid * 32 + g * 8) * 64);
    };

    auto compute = [&](int s) {
        const int slot = s & 1;
        const ushort* sa = &lds[slot][0];
        const ushort* sb = &lds[slot][8192];
        #pragma unroll
        for (int ks = 0; ks < 2; ++ks) {
            const int sw = ((ks * 4 + hi) ^ (fr & 7)) * 8;   // swizzled chunk
            v8bf a[4], b[4];
            #pragma unroll
            for (int m = 0; m < 4; m++)
                a[m] = *(const v8bf*)&sa[(wm * 64 + m * 16 + fr) * 64 + sw];
            #pragma unroll
            for (int n = 0; n < 4; n++)
                b[n] = *(const v8bf*)&sb[(wn * 64 + n * 16 + fr) * 64 + sw];
            __builtin_amdgcn_s_setprio(1);
            #pragma unroll
            for (int m = 0; m < 4; m++)
                #pragma unroll
                for (int n = 0; n < 4; n++)
                    acc[m][n] = __builtin_amdgcn_mfma_f32_16x16x32_bf16(a[m], b[n], acc[m][n], 0, 0, 0);
            __builtin_amdgcn_s_setprio(0);
        }
    };

    const int S = K >> 6;          // BK=64 slabs
    stage(0);                      // 8 loads in flight per wave

    for (int s = 0; s < S - 1; ++s) {
        stage(s + 1);                                    // other slot (readers of s-1 done)
        asm volatile("s_waitcnt vmcnt(8)" ::: "memory"); // slab-s loads landed; s+1 in flight
        __builtin_amdgcn_s_barrier();                    // all waves' slab-s loads landed
        compute(s);
        __builtin_amdgcn_s_barrier();                    // all reads of slot s&1 done
    }
    asm volatile("s_waitcnt vmcnt(0)" ::: "memory");
    __builtin_amdgcn_s_barrier();
    compute(S - 1);

    // epilogue: C/D layout col=lane&15, row=(lane>>4)*4+jj (m89-verified)
    const int cr  = (lane >> 4) * 4;
    const int cc2 = lane & 15;
    for (int m = 0; m < 4; m++)
        for (int n = 0; n < 4; n++) {
            long row = brow + wm * 64 + m * 16 + cr;
            long col = bcol + wn * 64 + n * 16 + cc2;
            for (int jj = 0; jj < 4; jj++)
                C[(row + jj) * (long)N + col] = f2bf(acc[m][n][jj]);
        }
}

// ---------------------------------------------------------------------------
// Fallback GEMM (round-4 proven): used for GEMM2 (K=64, too shallow to pipe).
// ---------------------------------------------------------------------------
#define BM 128
#define BN 128
#define BKK 32

template<int RELU>
__global__ __launch_bounds__(256)
void gemm_bt(const ushort* __restrict__ A, const ushort* __restrict__ B,
             ushort* __restrict__ C, int M, int N, int K)
{
    __shared__ ushort sA[BM * BKK];
    __shared__ ushort sB[BN * BKK];
    const int t    = threadIdx.x;
    const int lane = t & 63;
    const int wid  = t >> 6;

    int wg = blockIdx.y * gridDim.x + blockIdx.x;
    const int chunk = (gridDim.x * gridDim.y) >> 3;
    wg = (wg & 7) * chunk + (wg >> 3);
    const int bx = wg % gridDim.x;
    const int by = wg / gridDim.x;

    const int wr   = (wid >> 1) * 64;
    const int wc   = (wid & 1) * 64;
    const long brow = (long)by * BM;
    const long bcol = (long)bx * BN;

    const int ls = lane >> 2;
    const int lc = (lane & 3) * 8;
    const int srow = wid * 32;
    const ushort* pa = A + (brow + srow + ls) * (long)K + lc;
    const ushort* pb = B + (bcol + srow + ls) * (long)K + lc;
    ushort* la0 = &sA[srow * BKK];
    ushort* la1 = &sA[(srow + 16) * BKK];
    ushort* lb0 = &sB[srow * BKK];
    ushort* lb1 = &sB[(srow + 16) * BKK];

    f32x4 acc[4][4];
    const f32x4 z = {0.f, 0.f, 0.f, 0.f};
    for (int m = 0; m < 4; m++)
        for (int n = 0; n < 4; n++) acc[m][n] = z;

    const int fr = lane & 15;
    const int fk = (lane >> 4) * 8;

    for (int k0 = 0; k0 < K; k0 += BKK) {
        __syncthreads();
        gld16(pa + k0,           la0);
        gld16(pa + 16L * K + k0, la1);
        gld16(pb + k0,           lb0);
        gld16(pb + 16L * K + k0, lb1);
        __syncthreads();
        v8bf a[4], b[4];
        for (int m = 0; m < 4; m++)
            a[m] = *(const v8bf*)&sA[(wr + m * 16 + fr) * BKK + fk];
        for (int n = 0; n < 4; n++)
            b[n] = *(const v8bf*)&sB[(wc + n * 16 + fr) * BKK + fk];
        for (int m = 0; m < 4; m++)
            for (int n = 0; n < 4; n++)
                acc[m][n] = __builtin_amdgcn_mfma_f32_16x16x32_bf16(a[m], b[n], acc[m][n], 0, 0, 0);
    }

    const int cr  = (lane >> 4) * 4;
    const int cc2 = lane & 15;
    for (int m = 0; m < 4; m++)
        for (int n = 0; n < 4; n++) {
            long row = brow + wr + m * 16 + cr;
            long col = bcol + wc + n * 16 + cc2;
            for (int j = 0; j < 4; j++) {
                float v = acc[m][n][j];
                if (RELU) v = v > 0.f ? v : 0.f;
                C[(row + j) * (long)N + col] = f2bf(v);
            }
        }
}

// ---------------------------------------------------------------------------
// LN1: x1 = LayerNorm(x + attn)*g1 + b1 ; q = cos(x1[:, :64] + theta_ffn)
// ---------------------------------------------------------------------------
__global__ __launch_bounds__(256)
void ln1_kernel(const float* __restrict__ x, const ushort* __restrict__ attn,
                const float* __restrict__ g1, const float* __restrict__ b1,
                const float* __restrict__ theta_ffn,
                ushort* __restrict__ x1, ushort* __restrict__ q)
{
    const int row = blockIdx.x;
    const int t   = threadIdx.x;
    const long base = (long)row * 1024 + t * 4;
    float4  xu = *(const float4*)&x[base];
    ushort4 au = *(const ushort4*)&attn[base];
    float y0 = xu.x + bf2f(au.x);
    float y1 = xu.y + bf2f(au.y);
    float y2 = xu.z + bf2f(au.z);
    float y3 = xu.w + bf2f(au.w);
    float s  = y0 + y1 + y2 + y3;
    float ss = y0 * y0 + y1 * y1 + y2 * y2 + y3 * y3;
    for (int off = 32; off > 0; off >>= 1) {
        s  += __shfl_down(s, off, 64);
        ss += __shfl_down(ss, off, 64);
    }
    __shared__ float red[8];
    const int lane = t & 63, wid = t >> 6;
    if (lane == 0) { red[wid] = s; red[4 + wid] = ss; }
    __syncthreads();
    s  = red[0] + red[1] + red[2] + red[3];
    ss = red[4] + red[5] + red[6] + red[7];
    const float mu   = s * (1.0f / 1024.0f);
    const float var  = ss * (1.0f / 1024.0f) - mu * mu;
    const float rstd = rsqrtf(var + 1e-5f);
    float4 gu = *(const float4*)&g1[t * 4];
    float4 bu = *(const float4*)&b1[t * 4];
    float o0 = (y0 - mu) * rstd * gu.x + bu.x;
    float o1 = (y1 - mu) * rstd * gu.y + bu.y;
    float o2 = (y2 - mu) * rstd * gu.z + bu.z;
    float o3 = (y3 - mu) * rstd * gu.w + bu.w;
    ushort4 ou; ou.x = f2bf(o0); ou.y = f2bf(o1); ou.z = f2bf(o2); ou.w = f2bf(o3);
    *(ushort4*)&x1[base] = ou;
    if (t < 16) {
        float4 tu = *(const float4*)&theta_ffn[t * 4];
        ushort4 qu;
        qu.x = f2bf(cosf(o0 + tu.x));
        qu.y = f2bf(cosf(o1 + tu.y));
        qu.z = f2bf(cosf(o2 + tu.z));
        qu.w = f2bf(cosf(o3 + tu.w));
        *(ushort4*)&q[(long)row * 64 + t * 4] = qu;
    }
}

// ---------------------------------------------------------------------------
// LN2: out = LayerNorm(x1 + ffn)*g2 + b2   (d_out is FP32)
// ---------------------------------------------------------------------------
__global__ __launch_bounds__(256)
void ln2_kernel(const ushort* __restrict__ x1, const ushort* __restrict__ ffn,
                const float* __restrict__ g2, const float* __restrict__ b2,
                float* __restrict__ out)
{
    const int row = blockIdx.x;
    const int t   = threadIdx.x;
    const long base = (long)row * 1024 + t * 4;
    ushort4 xu = *(const ushort4*)&x1[base];
    ushort4 au = *(const ushort4*)&ffn[base];
    float y0 = bf2f(xu.x) + bf2f(au.x);
    float y1 = bf2f(xu.y) + bf2f(au.y);
    float y2 = bf2f(xu.z) + bf2f(au.z);
    float y3 = bf2f(xu.w) + bf2f(au.w);
    float s  = y0 + y1 + y2 + y3;
    float ss = y0 * y0 + y1 * y1 + y2 * y2 + y3 * y3;
    for (int off = 32; off > 0; off >>= 1) {
        s  += __shfl_down(s, off, 64);
        ss += __shfl_down(ss, off, 64);
    }
    __shared__ float red[8];
    const int lane = t & 63, wid = t >> 6;
    if (lane == 0) { red[wid] = s; red[4 + wid] = ss; }
    __syncthreads();
    s  = red[0] + red[1] + red[2] + red[3];
    ss = red[4] + red[5] + red[6] + red[7];
    const float mu   = s * (1.0f / 1024.0f);
    const float var  = ss * (1.0f / 1024.0f) - mu * mu;
    const float rstd = rsqrtf(var + 1e-5f);
    float4 gu = *(const float4*)&g2[t * 4];
    float4 bu = *(const float4*)&b2[t * 4];
    float4 ou;
    ou.x = (y0 - mu) * rstd * gu.x + bu.x;
    ou.y = (y1 - mu) * rstd * gu.y + bu.y;
    ou.z = (y2 - mu) * rstd * gu.z + bu.z;
    ou.w = (y3 - mu) * rstd * gu.w + bu.w;
    *(float4*)&out[base] = ou;
}

// ---------------------------------------------------------------------------
extern "C" void kernel_launch(void* const* d_in, const int* in_sizes, int n_in,
                              void* d_out, int out_size, void* d_ws, size_t ws_size,
                              hipStream_t stream)
{
    const int E = 1024, FFN = 4096;
    const long T = 8192;
    const long NE = T * E;

    const float* x       = (const float*)d_in[0];
    const float* th_attn = (const float*)d_in[1];
    const float* Wc      = (const float*)d_in[2];
    const float* g1      = (const float*)d_in[3];
    const float* b1      = (const float*)d_in[4];
    const float* th_ffn  = (const float*)d_in[5];
    const float* W1      = (const float*)d_in[6];
    const float* W2      = (const float*)d_in[7];
    const float* g2      = (const float*)d_in[8];
    const float* b2      = (const float*)d_in[9];
    float* out = (float*)d_out;

    ushort* ws   = (ushort*)d_ws;
    ushort* meas = ws;  ws += NE;
    ushort* attn = ws;  ws += NE;
    ushort* x1b  = ws;  ws += NE;
    ushort* q    = ws;  ws += T * 64;
    ushort* h    = ws;  ws += T * FFN;
    ushort* ffn  = ws;  ws += NE;
    ushort* wcb  = ws;  ws += (long)E * E;
    ushort* w1b  = ws;  ws += (long)FFN * 64;
    ushort* w2b  = meas;   // overlays meas (dead after GEMM1)
    if (ws_size < (size_t)((char*)ws - (char*)d_ws)) return;

    const long nWc = (long)E * E, nW1 = (long)FFN * 64, nW2 = (long)E * FFN;

    cvt_bf16_kernel<<<dim3((int)(nWc / 2048)), 256, 0, stream>>>(Wc, wcb, nWc);
    cvt_bf16_kernel<<<dim3((int)(nW1 / 2048)), 256, 0, stream>>>(W1, w1b, nW1);
    meas_kernel<<<dim3((int)(NE / 2048)), 256, 0, stream>>>(x, th_attn, meas, NE);
    // GEMM1: meas(8192x1024) @ Wc^T — pipelined (S=16), grid 8x64=512 (2/CU)
    gemm_pipe<<<dim3(E / 128, (int)(T / 128)), 256, 0, stream>>>(meas, wcb, attn, (int)T, E, E);
    cvt_bf16_kernel<<<dim3((int)(nW2 / 2048)), 256, 0, stream>>>(W2, w2b, nW2);
    ln1_kernel<<<dim3((int)T), 256, 0, stream>>>(x, attn, g1, b1, th_ffn, x1b, q);
    // GEMM2: K=64 too shallow for the pipe — round-4 kernel
    gemm_bt<1><<<dim3(FFN / BN, (int)(T / BM)), 256, 0, stream>>>(q, w1b, h, (int)T, FFN, 64);
    // GEMM3: h(8192x4096) @ W2^T — pipelined (S=64), grid 8x64=512 (2/CU)
    gemm_pipe<<<dim3(E / 128, (int)(T / 128)), 256, 0, stream>>>(h, w2b, ffn, (int)T, E, FFN);
    ln2_kernel<<<dim3((int)T), 256, 0, stream>>>(x1b, ffn, g2, b2, out);
}